// Round 1
// baseline (183.851 us; speedup 1.0000x reference)
//
#include <hip/hip_runtime.h>

// ---------------------------------------------------------------------------
// Attention_52424370815683: B=2, S=2048, D=1024, H=16, hd=64. f32 I/O.
//   k0: convert x|qkv_w|proj_w f32 -> bf16 (single merged launch)
//   k1: qkv GEMM, 512-thr in-block split-K (two 512-col halves, f32 LDS merge)
//       -> q[b,h,s,d], k (pre-scaled by 0.125*log2e), vT[b,h,d,s]
//   k2: flash attention, 128 q/block, 8 waves (16 q-rows each), ALL keys per
//       wave (no split-K/merge), double-buffered K/V staging with 2-phase
//       schedule: stage(t+1) -> compute(t) -> vmcnt+barrier. 1 barrier/tile.
//   k3: out(f32) = attn @ proj_w^T + proj_b, 128x64 tiles, 2-phase dbuf.
// ---------------------------------------------------------------------------

typedef __bf16 bf16_8 __attribute__((ext_vector_type(8)));
typedef __bf16 bf16_4 __attribute__((ext_vector_type(4)));
typedef __bf16 bf16_2 __attribute__((ext_vector_type(2)));
typedef float floatx4 __attribute__((ext_vector_type(4)));

#define MFMA16 __builtin_amdgcn_mfma_f32_16x16x32_bf16
#define CSCALE 0.1803368801111204f   // hd^-0.5 * log2(e)
#define EXP2R  __builtin_amdgcn_exp2f   // bare v_exp_f32 (no OCML denorm fixup)

__device__ __forceinline__ void gld16(const __bf16* g, __bf16* l) {
    __builtin_amdgcn_global_load_lds(
        (const __attribute__((address_space(1))) void*)g,
        (__attribute__((address_space(3))) void*)l, 16, 0, 0);
}

__device__ __forceinline__ unsigned pk_bf16(float a, float b) {
    bf16_2 t;
    t[0] = (__bf16)a; t[1] = (__bf16)b;
    return __builtin_bit_cast(unsigned, t);
}

// ---------------------------------------------------------------------------
// Kernel 0: merged f32 -> bf16 convert for x (1M f4), qkv_w (768K), proj_w
// (256K). Grid exactly 2M float4s / 256.
// ---------------------------------------------------------------------------
__global__ __launch_bounds__(256) void cvt_all(
    const float* __restrict__ x, const float* __restrict__ w1,
    const float* __restrict__ w2,
    __bf16* __restrict__ xb, __bf16* __restrict__ w1b, __bf16* __restrict__ w2b)
{
    const int i = blockIdx.x * 256 + threadIdx.x;     // float4 index
    const float* src; __bf16* dst; int off;
    if (i < (1 << 20))                  { src = x;  dst = xb;  off = i; }
    else if (i < (1 << 20) + 786432)    { src = w1; dst = w1b; off = i - (1 << 20); }
    else                                { src = w2; dst = w2b; off = i - (1 << 20) - 786432; }
    float4 v = ((const float4*)src)[off];
    bf16_4 o;
    o[0] = (__bf16)v.x; o[1] = (__bf16)v.y; o[2] = (__bf16)v.z; o[3] = (__bf16)v.w;
    ((bf16_4*)dst)[off] = o;
}

// ---------------------------------------------------------------------------
// Kernel 1: QKV GEMM, in-block split-K. M=4096, N=3072, K=1024. grid (24,32),
// 512 threads. half = tid>>8 takes K-cols [half*512, half*512+512) with its
// own 4-wave 128x128 mainloop + private 32 KB staging (total LDS 64 KB ->
// 2 blocks/CU = 16 waves/CU). Merge: half1 writes f32 acc into dead staging
// LDS (conflict-free b128 pattern), half0 adds + runs epilogue.
// q/k blocks (c<2): swapped operands -> d-contiguous packed stores, K channel
// pre-scaled by CSCALE. v blocks: vT[b,h,d,s] packs along s.
// ---------------------------------------------------------------------------
__global__ __launch_bounds__(512) void qkv_gemm(
    const __bf16* __restrict__ X, const __bf16* __restrict__ W,
    __bf16* __restrict__ q_ws, __bf16* __restrict__ k_ws, __bf16* __restrict__ vt_ws)
{
    __shared__ __align__(16) __bf16 S[2][2][128 * 64];  // [half][A/B][tile] 64 KB

    const int tid = threadIdx.x, lane = tid & 63;
    const int half = tid >> 8, htid = tid & 255;
    const int wvh = (tid >> 6) & 3;                 // wave within half
    const int quad = lane >> 4, l15 = lane & 15;
    const int wm = (wvh >> 1) * 64, wn = (wvh & 1) * 64;
    const int m0 = blockIdx.y * 128, n0 = blockIdx.x * 128;
    const int c = n0 >> 10;                         // 0=q 1=k 2=v (block-uniform)

    // A/B row bases for this half's K-columns (both K-major, stride 1024)
    const __bf16* Abase;
    const __bf16* Bbase;
    if (c == 2) { Abase = X + (size_t)m0 * 1024; Bbase = W + (size_t)n0 * 1024; }
    else        { Abase = W + (size_t)n0 * 1024; Bbase = X + (size_t)m0 * 1024; }
    Abase += half * 512;
    Bbase += half * 512;

    __bf16* As = S[half][0];
    __bf16* Bs = S[half][1];
    floatx4 acc[4][4] = {};

    for (int k0 = 0; k0 < 512; k0 += 64) {
        __syncthreads();
#pragma unroll
        for (int it = 0; it < 4; ++it) {
            int cc = it * 256 + htid;
            int row = cc >> 3, kc = cc & 7;
            gld16(Abase + row * 1024 + k0 + ((kc ^ (row & 7)) * 8), &As[cc * 8]);
        }
#pragma unroll
        for (int it = 0; it < 4; ++it) {
            int cc = it * 256 + htid;
            int row = cc >> 3, kc = cc & 7;
            gld16(Bbase + row * 1024 + k0 + ((kc ^ (row & 7)) * 8), &Bs[cc * 8]);
        }
        __syncthreads();

#pragma unroll
        for (int ks = 0; ks < 2; ++ks) {
            bf16_8 af[4], bf[4];
#pragma unroll
            for (int mt = 0; mt < 4; ++mt) {
                int r = wm + mt * 16 + l15;
                af[mt] = *(const bf16_8*)&As[r * 64 + (((ks * 4 + quad) ^ (r & 7)) * 8)];
            }
#pragma unroll
            for (int nt = 0; nt < 4; ++nt) {
                int r = wn + nt * 16 + l15;
                bf[nt] = *(const bf16_8*)&Bs[r * 64 + (((ks * 4 + quad) ^ (r & 7)) * 8)];
            }
#pragma unroll
            for (int mt = 0; mt < 4; ++mt)
#pragma unroll
                for (int nt = 0; nt < 4; ++nt)
                    acc[mt][nt] = MFMA16(af[mt], bf[nt], acc[mt][nt], 0, 0, 0);
        }
    }

    // ---- merge: half1 -> LDS f32 (overlay staging), half0 adds. Layout
    // [i4][htid] floatx4: consecutive lanes -> consecutive 16B, conflict-free.
    __syncthreads();
    float* comb = (float*)S;                        // 16*256*16 B = 64 KB exact
    if (half == 1) {
#pragma unroll
        for (int mt = 0; mt < 4; ++mt)
#pragma unroll
            for (int nt = 0; nt < 4; ++nt)
                *(floatx4*)&comb[((mt * 4 + nt) * 256 + htid) * 4] = acc[mt][nt];
    }
    __syncthreads();
    if (half != 0) return;

#pragma unroll
    for (int mt = 0; mt < 4; ++mt)
#pragma unroll
        for (int nt = 0; nt < 4; ++nt)
            acc[mt][nt] += *(const floatx4*)&comb[((mt * 4 + nt) * 256 + htid) * 4];

    if (c == 2) {
#pragma unroll
        for (int mt = 0; mt < 4; ++mt) {
            const int mbase = m0 + wm + mt * 16 + quad * 4;   // token, 4-aligned
            const int b = mbase >> 11, s = mbase & 2047;
#pragma unroll
            for (int nt = 0; nt < 4; ++nt) {
                const int n = n0 + wn + nt * 16 + l15;
                const int h = (n >> 6) & 15, d = n & 63;
                bf16_4 pk;
#pragma unroll
                for (int r = 0; r < 4; ++r) pk[r] = (__bf16)acc[mt][nt][r];
                *(bf16_4*)&vt_ws[((b * 16 + h) * 64 + d) * 2048 + s] = pk;
            }
        }
    } else {
        __bf16* dst = (c == 0) ? q_ws : k_ws;
        const float scale = (c == 1) ? CSCALE : 1.0f;
#pragma unroll
        for (int mt = 0; mt < 4; ++mt) {
            const int nn = n0 + wm + mt * 16 + quad * 4;      // n, 4-aligned
            const int h = (nn >> 6) & 15, d0 = nn & 63;
#pragma unroll
            for (int nt = 0; nt < 4; ++nt) {
                const int token = m0 + wn + nt * 16 + l15;
                const int b = token >> 11, s = token & 2047;
                bf16_4 pk;
#pragma unroll
                for (int r = 0; r < 4; ++r) pk[r] = (__bf16)(acc[mt][nt][r] * scale);
                *(bf16_4*)&dst[((b * 16 + h) * 2048 + s) * 64 + d0] = pk;
            }
        }
    }
}

// ---------------------------------------------------------------------------
// Kernel 2: flash attention. grid (32 bh, 16 qt), block = 512 (8 waves).
// Each wave owns 16 q-rows (w*16) and iterates ALL 32 key-tiles -> no
// split-K merge. K/V tiles double-buffered in LDS; 2-phase schedule per
// tile: issue stage(t+1) -> compute(t) -> vmcnt(0)+barrier. The vmcnt
// drain lands AFTER ~700cy of compute so HBM/L2 latency is hidden (the
// old structure drained vmcnt(0) immediately after issue, exposing full
// latency 16x per block). LDS 50 KB -> 2 blocks/CU resident (grid 512).
// No-max softmax (k pre-scaled by 0.125*log2e), l via ones-row MFMA.
// ---------------------------------------------------------------------------
__global__ __launch_bounds__(512) void attn_kernel(
    const __bf16* __restrict__ q_ws, const __bf16* __restrict__ k_ws,
    const __bf16* __restrict__ vt_ws, __bf16* __restrict__ attn_ws)
{
    __shared__ __align__(16) __bf16 Ks [2][64 * 64];    // [buf][key][d] swizzled
    __shared__ __align__(16) __bf16 Vts[2][64 * 64];    // [buf][d][key] swizzled
    __shared__ __align__(16) __bf16 Ps [8][16][72];     // [wave][q][key] 18 KB

    const int tid = threadIdx.x, lane = tid & 63, w = tid >> 6;   // w 0..7
    const int quad = lane >> 4, l15 = lane & 15;
    const int bh = blockIdx.x, qt = blockIdx.y;
    const int q0 = qt * 128;

    const __bf16* qp  = q_ws  + (size_t)bh * (2048 * 64);
    const __bf16* kp  = k_ws  + (size_t)bh * (2048 * 64);
    const __bf16* vtp = vt_ws + (size_t)bh * (64 * 2048);

    // staging: 512 threads x 1 gld16 each per tile (64 rows x 8 chunks).
    // loop-invariant per-lane bases; swizzle slot is row-parity invariant.
    const int srow = tid >> 3, skc = tid & 7;
    const int sw   = (skc ^ (srow & 7)) * 8;
    const __bf16* kb = kp  + (size_t)srow * 64 + sw;     // + kt*64*64
    const __bf16* vb = vtp + (size_t)srow * 2048 + sw;   // + kt*64
    const int ldsoff = tid * 8;                          // wave-uniform + lane*16B

    // Q B-frag for this wave's 16 q-rows, held in registers all loop
    bf16_8 qf[2];
    {
        const int qrow = q0 + w * 16 + l15;
        qf[0] = *(const bf16_8*)&qp[qrow * 64 + quad * 8];
        qf[1] = *(const bf16_8*)&qp[qrow * 64 + 32 + quad * 8];
    }

    bf16_8 ones;
#pragma unroll
    for (int j = 0; j < 8; ++j) ones[j] = (__bf16)1.0f;

    floatx4 oacc[4] = {};                   // [dg] Ot tiles, all 2048 keys
    floatx4 lsum = {};                      // ones-row MFMA accumulator

    // prologue: stage tile 0 into buf 0
    gld16(kb, &Ks[0][ldsoff]);
    gld16(vb, &Vts[0][ldsoff]);
    __syncthreads();                        // drains vmcnt(0): buf0 ready

#pragma unroll 2
    for (int kt = 0; kt < 32; ++kt) {
        const int cur = kt & 1;
        // ---- issue next tile's stage FIRST (latency hides under compute)
        if (kt < 31) {
            gld16(kb + (size_t)(kt + 1) * 4096, &Ks[cur ^ 1][ldsoff]);
            gld16(vb + (size_t)(kt + 1) * 64,   &Vts[cur ^ 1][ldsoff]);
        }
        const __bf16* Kb = Ks[cur];
        const __bf16* Vb = Vts[cur];

        // ---- St[key][q] = K . Q^T
        floatx4 sacc[4] = {};
        __builtin_amdgcn_s_setprio(1);
#pragma unroll
        for (int ks = 0; ks < 2; ++ks)
#pragma unroll
            for (int kg = 0; kg < 4; ++kg) {
                const int krow = kg * 16 + l15;
                bf16_8 kf = *(const bf16_8*)&Kb[krow * 64 + (((ks * 4 + quad) ^ (krow & 7)) * 8)];
                sacc[kg] = MFMA16(kf, qf[ks], sacc[kg], 0, 0, 0);
            }
        __builtin_amdgcn_s_setprio(0);

        // ---- p = exp2(score) via raw v_exp_f32, stash P (C -> B layout)
#pragma unroll
        for (int kg = 0; kg < 4; ++kg) {
            uint2 pk;
            pk.x = pk_bf16(EXP2R(sacc[kg][0]), EXP2R(sacc[kg][1]));
            pk.y = pk_bf16(EXP2R(sacc[kg][2]), EXP2R(sacc[kg][3]));
            *(uint2*)&Ps[w][l15][kg * 16 + quad * 4] = pk;
        }
        __asm__ __volatile__("s_waitcnt lgkmcnt(0)" ::: "memory");

        // ---- Ot[d][q] += Vt . P^T; l[q] += ones . P^T
        __builtin_amdgcn_s_setprio(1);
#pragma unroll
        for (int ks = 0; ks < 2; ++ks) {
            bf16_8 pf = *(const bf16_8*)&Ps[w][l15][ks * 32 + quad * 8];
            lsum = MFMA16(ones, pf, lsum, 0, 0, 0);
#pragma unroll
            for (int dg = 0; dg < 4; ++dg) {
                const int drow = dg * 16 + l15;
                bf16_8 vf = *(const bf16_8*)&Vb[drow * 64 + (((ks * 4 + quad) ^ (drow & 7)) * 8)];
                oacc[dg] = MFMA16(vf, pf, oacc[dg], 0, 0, 0);
            }
        }
        __builtin_amdgcn_s_setprio(0);

        // ---- single barrier per tile: my stage loads drained (hidden under
        // compute above) + everyone done reading buf[cur] -> safe to swap.
        if (kt < 31) {
            __asm__ __volatile__("s_waitcnt vmcnt(0)" ::: "memory");
            __syncthreads();
        }
    }

    // ---- epilogue: normalize + store (register-only, no merge needed)
    const int b = bh >> 4, h = bh & 15;
    const float inv_l = 1.0f / lsum[0];     // all rows of ones-MFMA identical
    const int token = b * 2048 + q0 + w * 16 + l15;
#pragma unroll
    for (int dg = 0; dg < 4; ++dg) {
        bf16_4 ok;
#pragma unroll
        for (int r = 0; r < 4; ++r) ok[r] = (__bf16)(oacc[dg][r] * inv_l);
        *(bf16_4*)&attn_ws[(size_t)token * 1024 + h * 64 + dg * 16 + quad * 4] = ok;
    }
}

// ---------------------------------------------------------------------------
// Kernel 3: proj GEMM + bias -> f32 out. M=4096, N=1024, K=1024.
// 128x64 tiles, grid (16, 32) = 512 blocks. 2-phase double-buffered staging
// (48 KB LDS -> 2 blocks/CU resident): stage(k+1) -> compute(k) -> barrier.
// ---------------------------------------------------------------------------
__device__ __forceinline__ void proj_stage(
    const __bf16* __restrict__ A, const __bf16* __restrict__ Bp,
    int k0, __bf16* As, __bf16* Bs, int tid)
{
#pragma unroll
    for (int it = 0; it < 4; ++it) {               // A: 128 rows x 8 chunks
        int cc = it * 256 + tid;
        int row = cc >> 3, kc = cc & 7;
        gld16(A + row * 1024 + k0 + ((kc ^ (row & 7)) * 8), &As[cc * 8]);
    }
#pragma unroll
    for (int it = 0; it < 2; ++it) {               // B: 64 rows x 8 chunks
        int cc = it * 256 + tid;
        int row = cc >> 3, kc = cc & 7;
        gld16(Bp + row * 1024 + k0 + ((kc ^ (row & 7)) * 8), &Bs[cc * 8]);
    }
}

__global__ __launch_bounds__(256) void proj_gemm(
    const __bf16* __restrict__ Ain, const __bf16* __restrict__ W,
    const float* __restrict__ bias, float* __restrict__ out)
{
    __shared__ __align__(16) __bf16 As[2][128 * 64];   // [buf][m][k] swizzled
    __shared__ __align__(16) __bf16 Bs[2][64 * 64];    // [buf][n][k] swizzled
    floatx4 acc[4][2] = {};
    const int m0 = blockIdx.y * 128, n0 = blockIdx.x * 64;

    const int tid = threadIdx.x, lane = tid & 63, wv = tid >> 6;
    const int quad = lane >> 4, l15 = lane & 15;
    const int wm = (wv >> 1) * 64, wn = (wv & 1) * 32;

    const __bf16* A  = Ain + (size_t)m0 * 1024;
    const __bf16* Bp = W   + (size_t)n0 * 1024;

    proj_stage(A, Bp, 0, As[0], Bs[0], tid);
    __syncthreads();

#pragma unroll 2
    for (int kk = 0; kk < 16; ++kk) {
        const int cur = kk & 1;
        if (kk < 15)
            proj_stage(A, Bp, (kk + 1) * 64, As[cur ^ 1], Bs[cur ^ 1], tid);

        const __bf16* Ab = As[cur];
        const __bf16* Bb = Bs[cur];
#pragma unroll
        for (int ks = 0; ks < 2; ++ks) {
            bf16_8 af[4], bf[2];
#pragma unroll
            for (int mt = 0; mt < 4; ++mt) {
                int r = wm + mt * 16 + l15;
                af[mt] = *(const bf16_8*)&Ab[r * 64 + (((ks * 4 + quad) ^ (r & 7)) * 8)];
            }
#pragma unroll
            for (int nt = 0; nt < 2; ++nt) {
                int r = wn + nt * 16 + l15;
                bf[nt] = *(const bf16_8*)&Bb[r * 64 + (((ks * 4 + quad) ^ (r & 7)) * 8)];
            }
#pragma unroll
            for (int mt = 0; mt < 4; ++mt)
#pragma unroll
                for (int nt = 0; nt < 2; ++nt)
                    acc[mt][nt] = MFMA16(af[mt], bf[nt], acc[mt][nt], 0, 0, 0);
        }

        if (kk < 15) {
            __asm__ __volatile__("s_waitcnt vmcnt(0)" ::: "memory");
            __syncthreads();
        }
    }

    float bv[2];
#pragma unroll
    for (int nt = 0; nt < 2; ++nt) bv[nt] = bias[n0 + wn + nt * 16 + l15];

#pragma unroll
    for (int mt = 0; mt < 4; ++mt) {
        const int m = m0 + wm + mt * 16 + quad * 4;
#pragma unroll
        for (int nt = 0; nt < 2; ++nt) {
            const int n = n0 + wn + nt * 16 + l15;
#pragma unroll
            for (int r = 0; r < 4; ++r)
                out[(size_t)(m + r) * 1024 + n] = acc[mt][nt][r] + bv[nt];
        }
    }
}

// ---------------------------------------------------------------------------
extern "C" void kernel_launch(void* const* d_in, const int* in_sizes, int n_in,
                              void* d_out, int out_size, void* d_ws, size_t ws_size,
                              hipStream_t stream)
{
    const float* x      = (const float*)d_in[0];
    const float* qkv_w  = (const float*)d_in[2];
    const float* proj_w = (const float*)d_in[3];
    const float* proj_b = (const float*)d_in[4];
    float* out = (float*)d_out;

    const size_t SZ   = 4096 * 1024;
    const size_t WQKV = 3072 * 1024;
    const size_t WPRJ = 1024 * 1024;

    __bf16* xb      = (__bf16*)d_ws;
    __bf16* qkvwb   = xb + SZ;
    __bf16* projwb  = qkvwb + WQKV;
    __bf16* q_ws    = projwb + WPRJ;
    __bf16* k_ws    = q_ws + SZ;
    __bf16* vt_ws   = k_ws + SZ;
    __bf16* attn_ws = vt_ws + SZ;

    cvt_all<<<dim3(8192), 256, 0, stream>>>(x, qkv_w, proj_w, xb, qkvwb, projwb);
    qkv_gemm  <<<dim3(24, 32), 512, 0, stream>>>(xb, qkvwb, q_ws, k_ws, vt_ws);
    attn_kernel<<<dim3(32, 16), 512, 0, stream>>>(q_ws, k_ws, vt_ws, attn_ws);
    proj_gemm <<<dim3(16, 32), 256, 0, stream>>>(attn_ws, projwb, proj_b, out);
}